// Round 1
// baseline (190.199 us; speedup 1.0000x reference)
//
#include <hip/hip_runtime.h>

#define POOL 100
#define PLEN 8
#define EMB 768
#define KEYD 768
#define BATCH 256
#define LD (PLEN*EMB)              // 6144
#define EK_FLOATS (BATCH*4*EMB)    // 786432
#define XB_FLOATS (BATCH*197*EMB)  // 38756352
#define LOSS_OFF (2*EK_FLOATS)     // 1572864
#define XB_OFF (LOSS_OFF+1)        // 1572865 (4B-aligned only!)

// G[k,k'] = <p[k,:,:], p[k',:,:]> over 6144 elems, double accumulation.
__global__ void kgram(const float* __restrict__ p, double* __restrict__ G) {
    int kx = blockIdx.x, ky = blockIdx.y;
    if (ky > kx) return;            // symmetric: compute lower-left only
    const float* a = p + (size_t)kx * LD;
    const float* b = p + (size_t)ky * LD;
    double acc = 0.0;
    for (int j = threadIdx.x; j < LD; j += 256)
        acc += (double)a[j] * (double)b[j];
    for (int off = 32; off > 0; off >>= 1)
        acc += __shfl_down(acc, off, 64);
    __shared__ double s[4];
    int lane = threadIdx.x & 63, w = threadIdx.x >> 6;
    if (lane == 0) s[w] = acc;
    __syncthreads();
    if (threadIdx.x == 0) {
        double t = s[0] + s[1] + s[2] + s[3];
        G[ky*POOL + kx] = t;
        G[kx*POOL + ky] = t;
    }
}

// per-b: cos_sim with normalized K rows (norm folded in, computed on the fly),
// then softmax -> alpha (double) in ws.
__global__ void kalpha(const float* __restrict__ xq, const float* __restrict__ K,
                       double* __restrict__ alpha) {
    int b = blockIdx.x;
    __shared__ float sx[KEYD];
    __shared__ double scos[POOL];
    __shared__ double sred[2];
    for (int j = threadIdx.x; j < KEYD; j += 256) sx[j] = xq[b*KEYD + j];
    __syncthreads();
    int w = threadIdx.x >> 6, lane = threadIdx.x & 63;
    for (int k = w; k < POOL; k += 4) {           // 4 waves x 25 pool rows
        const float* kr = K + k*KEYD;
        double dot = 0.0, sq = 0.0;
        for (int j = lane; j < KEYD; j += 64) {
            double kv = (double)kr[j];
            dot += kv * (double)sx[j];
            sq  += kv * kv;
        }
        for (int off = 32; off > 0; off >>= 1) {
            dot += __shfl_down(dot, off, 64);
            sq  += __shfl_down(sq,  off, 64);
        }
        if (lane == 0) {
            double nrm = sqrt(sq);
            if (nrm < 1e-12) nrm = 1e-12;
            scos[k] = dot / nrm;                   // SOFT_T == 1.0
        }
    }
    __syncthreads();
    if (threadIdx.x == 0) {
        double m = scos[0];
        for (int k = 1; k < POOL; ++k) m = fmax(m, scos[k]);
        sred[0] = m;
    }
    __syncthreads();
    if (threadIdx.x < POOL)
        scos[threadIdx.x] = exp(scos[threadIdx.x] - sred[0]);
    __syncthreads();
    if (threadIdx.x == 0) {
        double ssum = 0.0;
        for (int k = 0; k < POOL; ++k) ssum += scos[k];
        sred[1] = ssum;
    }
    __syncthreads();
    if (threadIdx.x < POOL)
        alpha[b*POOL + threadIdx.x] = scos[threadIdx.x] / sred[1];
}

// per-b: cross = alpha @ G, argmin_k(G[k,k]-2*cross), pa_sq = <alpha,cross>,
// dist term for loss, and gather p[idx] -> Ek/Ev.
__global__ void kvq(const double* __restrict__ alpha, const double* __restrict__ G,
                    const float* __restrict__ p, float* __restrict__ out,
                    double* __restrict__ dterm) {
    int b = blockIdx.x;
    __shared__ double sa[POOL], scr[POOL], sm[POOL];
    __shared__ int sidx;
    if (threadIdx.x < POOL) sa[threadIdx.x] = alpha[b*POOL + threadIdx.x];
    __syncthreads();
    if (threadIdx.x < POOL) {
        double c = 0.0;
        for (int k = 0; k < POOL; ++k)
            c += sa[k] * G[k*POOL + threadIdx.x];   // coalesced over t
        scr[threadIdx.x] = c;
        sm[threadIdx.x]  = G[threadIdx.x*POOL + threadIdx.x] - 2.0*c;
    }
    __syncthreads();
    if (threadIdx.x == 0) {
        int best = 0; double bm = sm[0]; double pa = sa[0]*scr[0];
        for (int k = 1; k < POOL; ++k) {
            pa += sa[k]*scr[k];
            if (sm[k] < bm) { bm = sm[k]; best = k; }  // first-index tiebreak, matches argmin
        }
        sidx = best;
        dterm[b] = pa + bm;    // = pa_sq - 2*cross[idx] + pp_sq[idx]
    }
    __syncthreads();
    int idx = sidx;
    const float4* src = (const float4*)(p + (size_t)idx * LD);
    float4* ek = (float4*)out;
    float4* ev = (float4*)(out + EK_FLOATS);
    for (int j = threadIdx.x; j < LD/4; j += 256) { // 1536 float4
        float4 v = src[j];
        int l = j / (EMB/4);        // prompt-slot 0..7
        int r = j % (EMB/4);
        if (l < 4) ek[b*EMB + l*(EMB/4) + r] = v;
        else       ev[b*EMB + (l-4)*(EMB/4) + r] = v;
    }
}

__global__ void kloss(const double* __restrict__ dterm, float* __restrict__ out) {
    double v = dterm[threadIdx.x];          // exactly 256 threads
    for (int off = 32; off > 0; off >>= 1) v += __shfl_down(v, off, 64);
    __shared__ double s[4];
    int lane = threadIdx.x & 63, w = threadIdx.x >> 6;
    if (lane == 0) s[w] = v;
    __syncthreads();
    if (threadIdx.x == 0) {
        double msq = (s[0]+s[1]+s[2]+s[3]) / (double)(BATCH * PLEN * EMB);
        out[LOSS_OFF] = (float)(0.5 * msq);  // 0.4*e + 0.1*q, e==q numerically
    }
}

// x_block passthrough. Dst starts at 4B-aligned-only offset: 3-float head,
// then scalar-load / float4-store aligned bulk, 1-float tail.
__global__ void kcopy(const float* __restrict__ xb, float* __restrict__ out) {
    const size_t n4 = (size_t)(XB_FLOATS - 3) / 4;   // 9689087
    float4* dst4 = (float4*)(out + XB_OFF + 3);      // 16B aligned
    size_t gt = (size_t)blockIdx.x * blockDim.x + threadIdx.x;
    size_t stride = (size_t)gridDim.x * blockDim.x;
    for (size_t i = gt; i < n4; i += stride) {
        size_t e = 3 + 4*i;
        float4 v;
        v.x = xb[e]; v.y = xb[e+1]; v.z = xb[e+2]; v.w = xb[e+3];
        dst4[i] = v;
    }
    if (gt == 0) {
        out[XB_OFF]   = xb[0];
        out[XB_OFF+1] = xb[1];
        out[XB_OFF+2] = xb[2];
        out[XB_OFF + XB_FLOATS - 1] = xb[XB_FLOATS - 1];
    }
}

extern "C" void kernel_launch(void* const* d_in, const int* in_sizes, int n_in,
                              void* d_out, int out_size, void* d_ws, size_t ws_size,
                              hipStream_t stream) {
    const float* xq = (const float*)d_in[0];
    // d_in[1] = l (always 0, in E_LAYERS)
    const float* xb = (const float*)d_in[2];
    const float* K  = (const float*)d_in[3];
    const float* p  = (const float*)d_in[4];
    float* out = (float*)d_out;

    double* G     = (double*)d_ws;        // 100*100 doubles = 80 KB
    double* alpha = G + POOL*POOL;        // 256*100 doubles = 200 KB
    double* dterm = alpha + BATCH*POOL;   // 256 doubles

    kgram<<<dim3(POOL, POOL), 256, 0, stream>>>(p, G);
    kalpha<<<BATCH, 256, 0, stream>>>(xq, K, alpha);
    kvq<<<BATCH, 256, 0, stream>>>(alpha, G, p, out, dterm);
    kloss<<<1, 256, 0, stream>>>(dterm, out);
    kcopy<<<2048, 256, 0, stream>>>(xb, out);
}

// Round 2
// 101.322 us; speedup vs baseline: 1.8772x; 1.8772x over previous
//
#include <hip/hip_runtime.h>

#define POOL 100
#define PLEN 8
#define EMB 768
#define KEYD 768
#define BATCH 256
#define LD (PLEN*EMB)              // 6144
#define EK_FLOATS (BATCH*4*EMB)    // 786432
#define XB_FLOATS (BATCH*197*EMB)  // 38756352
#define LOSS_OFF (2*EK_FLOATS)     // 1572864
#define XB_OFF (LOSS_OFF+1)        // 1572865 (4B-aligned only!)

// rn[k] = 1 / max(||K[k]||, 1e-12), one wave per pool row
__global__ void knorm(const float* __restrict__ K, double* __restrict__ rn) {
    int k = blockIdx.x, lane = threadIdx.x;          // 64 threads
    const float4* kr = (const float4*)(K + (size_t)k * KEYD);
    double sq = 0.0;
    #pragma unroll
    for (int t = 0; t < 3; ++t) {                    // 192 float4 per row
        float4 a = kr[t*64 + lane];
        sq += (double)a.x*a.x + (double)a.y*a.y + (double)a.z*a.z + (double)a.w*a.w;
    }
    for (int off = 32; off > 0; off >>= 1) sq += __shfl_down(sq, off, 64);
    if (lane == 0) rn[k] = 1.0 / fmax(sqrt(sq), 1e-12);
}

// G[k,k'] = <p[k,:,:], p[k',:,:]> over 6144 elems, f32 loads vectorized, f64 acc.
__global__ void kgram(const float* __restrict__ p, double* __restrict__ G) {
    int kx = blockIdx.x, ky = blockIdx.y;
    if (ky > kx) return;            // symmetric: lower-left only
    const float4* a = (const float4*)(p + (size_t)kx * LD);
    const float4* b = (const float4*)(p + (size_t)ky * LD);
    double acc = 0.0;
    for (int j = threadIdx.x; j < LD/4; j += 256) {  // 1536 float4, 6 per thread
        float4 va = a[j], vb = b[j];
        acc += (double)va.x*vb.x + (double)va.y*vb.y + (double)va.z*vb.z + (double)va.w*vb.w;
    }
    for (int off = 32; off > 0; off >>= 1) acc += __shfl_down(acc, off, 64);
    __shared__ double s[4];
    int lane = threadIdx.x & 63, w = threadIdx.x >> 6;
    if (lane == 0) s[w] = acc;
    __syncthreads();
    if (threadIdx.x == 0) {
        double t = s[0] + s[1] + s[2] + s[3];
        G[ky*POOL + kx] = t;
        G[kx*POOL + ky] = t;
    }
}

// cos[b,k] = <xq[b], K[k]> * rn[k]. One wave per (b,k): grid (B, 25) x 4 waves.
__global__ void kcos(const float* __restrict__ xq, const float* __restrict__ K,
                     const double* __restrict__ rn, double* __restrict__ cosm) {
    int b = blockIdx.x;
    int w = threadIdx.x >> 6, lane = threadIdx.x & 63;
    int k = blockIdx.y * 4 + w;                      // 25*4 = 100
    const float4* kr = (const float4*)(K + (size_t)k * KEYD);
    const float4* xr = (const float4*)(xq + (size_t)b * KEYD);
    double dot = 0.0;
    #pragma unroll
    for (int t = 0; t < 3; ++t) {
        float4 a = kr[t*64 + lane];
        float4 x = xr[t*64 + lane];
        dot += (double)a.x*x.x + (double)a.y*x.y + (double)a.z*x.z + (double)a.w*x.w;
    }
    for (int off = 32; off > 0; off >>= 1) dot += __shfl_down(dot, off, 64);
    if (lane == 0) cosm[(size_t)b*POOL + k] = dot * rn[k];
}

// per-b: softmax(cos) -> alpha, cross = alpha@G, argmin_k(G[k,k]-2*cross),
// dterm = pa_sq + min-dist-term, gather p[idx] -> Ek/Ev.
__global__ void kvq(const double* __restrict__ cosm, const double* __restrict__ G,
                    const float* __restrict__ p, float* __restrict__ out,
                    double* __restrict__ dterm) {
    int b = blockIdx.x;
    __shared__ double sa[POOL], scr[POOL], sm[POOL];
    __shared__ double sred[2];
    __shared__ int sidx;
    if (threadIdx.x < POOL) sa[threadIdx.x] = cosm[(size_t)b*POOL + threadIdx.x];
    __syncthreads();
    if (threadIdx.x == 0) {                      // softmax max
        double m = sa[0];
        for (int k = 1; k < POOL; ++k) m = fmax(m, sa[k]);
        sred[0] = m;
    }
    __syncthreads();
    if (threadIdx.x < POOL) sa[threadIdx.x] = exp(sa[threadIdx.x] - sred[0]);
    __syncthreads();
    if (threadIdx.x == 0) {                      // softmax sum
        double ssum = 0.0;
        for (int k = 0; k < POOL; ++k) ssum += sa[k];
        sred[1] = ssum;
    }
    __syncthreads();
    if (threadIdx.x < POOL) sa[threadIdx.x] /= sred[1];   // alpha
    __syncthreads();
    if (threadIdx.x < POOL) {
        double c = 0.0;
        for (int k = 0; k < POOL; ++k)
            c += sa[k] * G[k*POOL + threadIdx.x];   // coalesced over tid
        scr[threadIdx.x] = c;
        sm[threadIdx.x]  = G[threadIdx.x*POOL + threadIdx.x] - 2.0*c;
    }
    __syncthreads();
    if (threadIdx.x == 0) {
        int best = 0; double bm = sm[0]; double pa = sa[0]*scr[0];
        for (int k = 1; k < POOL; ++k) {
            pa += sa[k]*scr[k];
            if (sm[k] < bm) { bm = sm[k]; best = k; }  // first-index tiebreak = np.argmin
        }
        sidx = best;
        dterm[b] = pa + bm;    // = pa_sq - 2*cross[idx] + pp_sq[idx]
    }
    __syncthreads();
    int idx = sidx;
    const float4* src = (const float4*)(p + (size_t)idx * LD);
    float4* ek = (float4*)out;
    float4* ev = (float4*)(out + EK_FLOATS);
    for (int j = threadIdx.x; j < LD/4; j += 256) { // 1536 float4
        float4 v = src[j];
        int l = j / (EMB/4);        // prompt-slot 0..7
        int r = j % (EMB/4);
        if (l < 4) ek[b*EMB + l*(EMB/4) + r] = v;
        else       ev[b*EMB + (l-4)*(EMB/4) + r] = v;
    }
}

__global__ void kloss(const double* __restrict__ dterm, float* __restrict__ out) {
    double v = dterm[threadIdx.x];          // exactly 256 threads
    for (int off = 32; off > 0; off >>= 1) v += __shfl_down(v, off, 64);
    __shared__ double s[4];
    int lane = threadIdx.x & 63, w = threadIdx.x >> 6;
    if (lane == 0) s[w] = v;
    __syncthreads();
    if (threadIdx.x == 0) {
        double msq = (s[0]+s[1]+s[2]+s[3]) / (double)(BATCH * PLEN * EMB);
        out[LOSS_OFF] = (float)(0.5 * msq);  // 0.4*e + 0.1*q, e==q numerically
    }
}

// x_block passthrough. Dst starts at 4B-aligned-only offset: 3-float head,
// then scalar-load / float4-store aligned bulk, 1-float tail.
__global__ void kcopy(const float* __restrict__ xb, float* __restrict__ out) {
    const size_t n4 = (size_t)(XB_FLOATS - 3) / 4;   // 9689087
    float4* dst4 = (float4*)(out + XB_OFF + 3);      // 16B aligned
    size_t gt = (size_t)blockIdx.x * blockDim.x + threadIdx.x;
    size_t stride = (size_t)gridDim.x * blockDim.x;
    for (size_t i = gt; i < n4; i += stride) {
        size_t e = 3 + 4*i;
        float4 v;
        v.x = xb[e]; v.y = xb[e+1]; v.z = xb[e+2]; v.w = xb[e+3];
        dst4[i] = v;
    }
    if (gt == 0) {
        out[XB_OFF]   = xb[0];
        out[XB_OFF+1] = xb[1];
        out[XB_OFF+2] = xb[2];
        out[XB_OFF + XB_FLOATS - 1] = xb[XB_FLOATS - 1];
    }
}

extern "C" void kernel_launch(void* const* d_in, const int* in_sizes, int n_in,
                              void* d_out, int out_size, void* d_ws, size_t ws_size,
                              hipStream_t stream) {
    const float* xq = (const float*)d_in[0];
    // d_in[1] = l (always 0, in E_LAYERS)
    const float* xb = (const float*)d_in[2];
    const float* K  = (const float*)d_in[3];
    const float* p  = (const float*)d_in[4];
    float* out = (float*)d_out;

    double* G     = (double*)d_ws;        // 100*100 doubles = 80 KB
    double* cosm  = G + POOL*POOL;        // 256*100 doubles = 200 KB
    double* dterm = cosm + BATCH*POOL;    // 256 doubles
    double* rn    = dterm + BATCH;        // 100 doubles

    knorm<<<POOL, 64, 0, stream>>>(K, rn);
    kgram<<<dim3(POOL, POOL), 256, 0, stream>>>(p, G);
    kcos<<<dim3(BATCH, 25), 256, 0, stream>>>(xq, K, rn, cosm);
    kvq<<<BATCH, 256, 0, stream>>>(cosm, G, p, out, dterm);
    kloss<<<1, 256, 0, stream>>>(dterm, out);
    kcopy<<<2048, 256, 0, stream>>>(xb, out);
}

// Round 3
// 95.687 us; speedup vs baseline: 1.9877x; 1.0589x over previous
//
#include <hip/hip_runtime.h>

#define POOL 100
#define PLEN 8
#define EMB 768
#define KEYD 768
#define BATCH 256
#define LD (PLEN*EMB)              // 6144
#define EK_FLOATS (BATCH*4*EMB)    // 786432
#define XB_FLOATS (BATCH*197*EMB)  // 38756352
#define LOSS_OFF (2*EK_FLOATS)     // 1572864
#define XB_OFF (LOSS_OFF+1)        // 1572865 (4B-aligned only!)
#define NGRAM 5050                 // 100*101/2 triangular pairs
#define NCOS (BATCH*25)            // 6400 blocks, 4 waves x (25 k's) each

// Fused prep: blocks [0,NGRAM) compute Gram pairs; blocks [NGRAM, NGRAM+NCOS)
// compute cos[b,k] = <xq[b],K[k]> / max(||K[k]||,1e-12)  (norm fused, f64).
__global__ void kprep(const float* __restrict__ p, const float* __restrict__ xq,
                      const float* __restrict__ K, double* __restrict__ G,
                      double* __restrict__ cosm, double* __restrict__ lossAcc,
                      unsigned int* __restrict__ lossCnt) {
    int t = blockIdx.x;
    if (t == 0 && threadIdx.x == 0) { lossAcc[0] = 0.0; lossCnt[0] = 0u; }
    if (t < NGRAM) {
        // triangular index -> (kx,ky), ky <= kx
        int kx = (int)((sqrt(8.0 * t + 1.0) - 1.0) * 0.5);
        while ((kx + 1) * (kx + 2) / 2 <= t) ++kx;
        while (kx * (kx + 1) / 2 > t) --kx;
        int ky = t - kx * (kx + 1) / 2;
        const float4* a = (const float4*)(p + (size_t)kx * LD);
        const float4* b = (const float4*)(p + (size_t)ky * LD);
        double acc = 0.0;
        #pragma unroll
        for (int it = 0; it < 6; ++it) {             // 1536 float4 / 256 thr
            int j = it * 256 + threadIdx.x;
            float4 va = a[j], vb = b[j];
            acc += (double)va.x*vb.x + (double)va.y*vb.y
                 + (double)va.z*vb.z + (double)va.w*vb.w;
        }
        for (int off = 32; off > 0; off >>= 1) acc += __shfl_down(acc, off, 64);
        __shared__ double s[4];
        int lane = threadIdx.x & 63, w = threadIdx.x >> 6;
        if (lane == 0) s[w] = acc;
        __syncthreads();
        if (threadIdx.x == 0) {
            double v = s[0] + s[1] + s[2] + s[3];
            G[ky * POOL + kx] = v;
            G[kx * POOL + ky] = v;
        }
    } else {
        int c = t - NGRAM;
        int b = c / 25, kg = c % 25;
        int w = threadIdx.x >> 6, lane = threadIdx.x & 63;
        int k = kg * 4 + w;                          // < 100 always
        const float4* kr = (const float4*)(K + (size_t)k * KEYD);
        const float4* xr = (const float4*)(xq + (size_t)b * KEYD);
        double dot = 0.0, sq = 0.0;
        #pragma unroll
        for (int it = 0; it < 3; ++it) {             // 192 float4 per row
            float4 a = kr[it * 64 + lane];
            float4 x = xr[it * 64 + lane];
            dot += (double)a.x*x.x + (double)a.y*x.y + (double)a.z*x.z + (double)a.w*x.w;
            sq  += (double)a.x*a.x + (double)a.y*a.y + (double)a.z*a.z + (double)a.w*a.w;
        }
        for (int off = 32; off > 0; off >>= 1) {
            dot += __shfl_down(dot, off, 64);
            sq  += __shfl_down(sq,  off, 64);
        }
        if (lane == 0)
            cosm[(size_t)b * POOL + k] = dot / fmax(sqrt(sq), 1e-12);
    }
}

// per-b: softmax(cos) -> alpha, cross = alpha@G, argmin_k(G[k,k]-2*cross),
// loss contribution via device atomics (last block writes loss), gather
// p[idx] -> Ek/Ev.
__global__ void kvq(const double* __restrict__ cosm, const double* __restrict__ G,
                    const float* __restrict__ p, float* __restrict__ out,
                    double* __restrict__ lossAcc, unsigned int* __restrict__ lossCnt) {
    int b = blockIdx.x;
    __shared__ double sa[POOL], scr[POOL], sm[POOL];
    __shared__ double sred[2];
    __shared__ int sidx;
    if (threadIdx.x < POOL) sa[threadIdx.x] = cosm[(size_t)b * POOL + threadIdx.x];
    __syncthreads();
    if (threadIdx.x == 0) {                      // softmax max
        double m = sa[0];
        for (int k = 1; k < POOL; ++k) m = fmax(m, sa[k]);
        sred[0] = m;
    }
    __syncthreads();
    if (threadIdx.x < POOL) sa[threadIdx.x] = exp(sa[threadIdx.x] - sred[0]);
    __syncthreads();
    if (threadIdx.x == 0) {                      // softmax sum
        double ssum = 0.0;
        for (int k = 0; k < POOL; ++k) ssum += sa[k];
        sred[1] = ssum;
    }
    __syncthreads();
    if (threadIdx.x < POOL) sa[threadIdx.x] /= sred[1];   // alpha
    __syncthreads();
    if (threadIdx.x < POOL) {
        double c = 0.0;
        for (int k = 0; k < POOL; ++k)
            c += sa[k] * G[k * POOL + threadIdx.x];   // coalesced over tid
        scr[threadIdx.x] = c;
        sm[threadIdx.x]  = G[threadIdx.x * POOL + threadIdx.x] - 2.0 * c;
    }
    __syncthreads();
    if (threadIdx.x == 0) {
        int best = 0; double bm = sm[0]; double pa = sa[0] * scr[0];
        for (int k = 1; k < POOL; ++k) {
            pa += sa[k] * scr[k];
            if (sm[k] < bm) { bm = sm[k]; best = k; }  // first-index tiebreak = np.argmin
        }
        sidx = best;
        double dterm = pa + bm;    // = pa_sq - 2*cross[idx] + pp_sq[idx]
        atomicAdd(lossAcc, dterm);
        __threadfence();
        unsigned int old = atomicAdd(lossCnt, 1u);
        if (old == BATCH - 1) {
            double total = atomicAdd(lossAcc, 0.0);   // fresh read
            double msq = total / (double)(BATCH * PLEN * EMB);
            out[LOSS_OFF] = (float)(0.5 * msq);       // 0.4*e + 0.1*q, e==q numerically
        }
    }
    __syncthreads();
    int idx = sidx;
    const float4* src = (const float4*)(p + (size_t)idx * LD);
    float4* ek = (float4*)out;
    float4* ev = (float4*)(out + EK_FLOATS);
    for (int j = threadIdx.x; j < LD / 4; j += 256) { // 1536 float4
        float4 v = src[j];
        int l = j / (EMB / 4);        // prompt-slot 0..7
        int r = j % (EMB / 4);
        if (l < 4) ek[b * EMB + l * (EMB / 4) + r] = v;
        else       ev[b * EMB + (l - 4) * (EMB / 4) + r] = v;
    }
}

// x_block passthrough, both sides 16B-aligned float4:
// dst4[j] = {src4[j].w, src4[j+1].x, src4[j+1].y, src4[j+1].z};
// src4[j].w comes from the wave neighbor via shfl_up (lane 0: scalar load).
__global__ void kcopy(const float* __restrict__ xb, float* __restrict__ out) {
    const size_t n4 = (size_t)(XB_FLOATS - 3) / 4;   // 9689087
    const float4* src4 = (const float4*)xb;          // 16B aligned
    float4* dst4 = (float4*)(out + XB_OFF + 3);      // 16B aligned
    size_t gt = (size_t)blockIdx.x * blockDim.x + threadIdx.x;
    size_t stride = (size_t)gridDim.x * blockDim.x;
    int lane = threadIdx.x & 63;
    for (size_t j = gt; j < n4; j += stride) {
        float4 v = src4[j + 1];
        float pw = __shfl_up(v.w, 1, 64);            // neighbor's src4[j].w
        if (lane == 0) pw = xb[4 * j + 3];
        float4 o; o.x = pw; o.y = v.x; o.z = v.y; o.w = v.z;
        dst4[j] = o;
    }
    if (gt == 0) {
        out[XB_OFF]     = xb[0];
        out[XB_OFF + 1] = xb[1];
        out[XB_OFF + 2] = xb[2];
        out[XB_OFF + XB_FLOATS - 1] = xb[XB_FLOATS - 1];
    }
}

extern "C" void kernel_launch(void* const* d_in, const int* in_sizes, int n_in,
                              void* d_out, int out_size, void* d_ws, size_t ws_size,
                              hipStream_t stream) {
    const float* xq = (const float*)d_in[0];
    // d_in[1] = l (always 0, in E_LAYERS)
    const float* xb = (const float*)d_in[2];
    const float* K  = (const float*)d_in[3];
    const float* p  = (const float*)d_in[4];
    float* out = (float*)d_out;

    double* G        = (double*)d_ws;          // 100*100 doubles = 80 KB
    double* cosm     = G + POOL * POOL;        // 256*100 doubles = 200 KB
    double* lossAcc  = cosm + BATCH * POOL;    // 1 double
    unsigned int* lossCnt = (unsigned int*)(lossAcc + 1);

    kprep<<<NGRAM + NCOS, 256, 0, stream>>>(p, xq, K, G, cosm, lossAcc, lossCnt);
    kvq<<<BATCH, 256, 0, stream>>>(cosm, G, p, out, lossAcc, lossCnt);
    kcopy<<<2048, 256, 0, stream>>>(xb, out);
}